// Round 7
// baseline (1821.290 us; speedup 1.0000x reference)
//
#include <hip/hip_runtime.h>

#define NN 100000   // nodes
#define EE 500000   // edges per relation
#define RR 3        // relations
#define LL 2        // layers
#define FF 300      // input features
#define HH 256      // hidden
#define CC 23       // classes
#define MPAD 100096 // 782 * 128
#define SCHUNK 2048
#define SNB ((NN + SCHUNK - 1) / SCHUNK)   // 49

static inline int cdiv_h(int a, int b) { return (a + b - 1) / b; }

typedef __attribute__((ext_vector_type(8))) short bf16x8;
typedef __attribute__((ext_vector_type(4))) float f32x4;

__device__ inline unsigned short f2bf(float f) {
    union { float f; unsigned int u; } v; v.f = f;
    unsigned int r = v.u + 0x7fff + ((v.u >> 16) & 1);
    return (unsigned short)(r >> 16);
}
__device__ inline float bf2f(unsigned short u) {
    union { unsigned int u; float f; } v; v.u = ((unsigned int)u) << 16;
    return v.f;
}

// ---------------------------------------------------------------------------
// CSR build
// ---------------------------------------------------------------------------
__global__ void hist_kernel(const int* __restrict__ src, const int* __restrict__ dst,
                            int* __restrict__ cnt_out, int* __restrict__ cnt_in,
                            int RE, int Eper) {
    int i = blockIdx.x * blockDim.x + threadIdx.x;
    if (i >= RE) return;
    int r = i / Eper;
    atomicAdd(&cnt_out[r * NN + src[i]], 1);
    atomicAdd(&cnt_in[r * NN + dst[i]], 1);
}

__global__ void rs_kernel(const int* __restrict__ cnt_out, const int* __restrict__ cnt_in,
                          float* __restrict__ rs_out, float* __restrict__ rs_in, int total) {
    int i = blockIdx.x * blockDim.x + threadIdx.x;
    if (i >= total) return;
    rs_out[i] = rsqrtf(fmaxf((float)cnt_out[i], 1.0f));
    rs_in[i]  = rsqrtf(fmaxf((float)cnt_in[i], 1.0f));
}

// --- 3-phase exclusive scan of in-degree counts -> CSR offsets + cursors ---
__global__ __launch_bounds__(256) void scan_a(const int* __restrict__ cnt, int* __restrict__ bsum) {
    int r = blockIdx.y, b = blockIdx.x, t = threadIdx.x;
    const int* c = cnt + (size_t)r * NN;
    int base = b * SCHUNK;
    int s = 0;
    for (int i = t; i < SCHUNK; i += 256) {
        int idx = base + i;
        if (idx < NN) s += c[idx];
    }
#pragma unroll
    for (int o = 1; o < 64; o <<= 1) s += __shfl_xor(s, o);
    __shared__ int sh[4];
    if ((t & 63) == 0) sh[t >> 6] = s;
    __syncthreads();
    if (t == 0) bsum[r * SNB + b] = sh[0] + sh[1] + sh[2] + sh[3];
}

__global__ void scan_b(int* __restrict__ bsum, int* __restrict__ offs) {
    int r = threadIdx.x;
    if (r >= RR) return;
    int* bs = bsum + r * SNB;
    int run = 0;
    for (int i = 0; i < SNB; i++) { int v = bs[i]; bs[i] = run; run += v; }
    offs[(size_t)r * (NN + 1) + NN] = run;
}

__global__ __launch_bounds__(256) void scan_c(const int* __restrict__ cnt, const int* __restrict__ bsum,
                                              int* __restrict__ offs, int* __restrict__ cur) {
    int r = blockIdx.y, b = blockIdx.x, t = threadIdx.x;
    const int* c = cnt + (size_t)r * NN;
    int base = b * SCHUNK + t * 8;
    int v[8]; int s = 0;
#pragma unroll
    for (int j = 0; j < 8; j++) {
        int idx = base + j;
        v[j] = (idx < NN) ? c[idx] : 0;
        s += v[j];
    }
    __shared__ int sh[256];
    sh[t] = s;
    __syncthreads();
    for (int d = 1; d < 256; d <<= 1) {
        int x = (t >= d) ? sh[t - d] : 0;
        __syncthreads();
        sh[t] += x;
        __syncthreads();
    }
    int run = sh[t] - s + bsum[r * SNB + b];
    int* orow = offs + (size_t)r * (NN + 1);
    int* crow = cur + (size_t)r * NN;
#pragma unroll
    for (int j = 0; j < 8; j++) {
        int idx = base + j;
        if (idx < NN) { orow[idx] = run; crow[idx] = run; }
        run += v[j];
    }
}

// Fill packed edge stream: (src, rs_out[src]) per edge, bucketed by dst.
__global__ void fill_kernel(const int* __restrict__ src, const int* __restrict__ dst,
                            const float* __restrict__ rs_out,
                            int* __restrict__ cur, int2* __restrict__ srcw,
                            int RE, int Eper) {
    int i = blockIdx.x * blockDim.x + threadIdx.x;
    if (i >= RE) return;
    int r = i / Eper;
    int d = dst[i];
    int s = src[i];
    float w = rs_out[r * NN + s];
    int pos = atomicAdd(&cur[r * NN + d], 1);
    srcw[(size_t)r * Eper + pos] = make_int2(s, __float_as_int(w));
}

// ---------------------------------------------------------------------------
// Weight prep: fp32 -> bf16, transposed to n-major [Ncols][K]
// ---------------------------------------------------------------------------
__global__ void convert_x(const float* __restrict__ x, unsigned short* __restrict__ xpad) {
    int row = blockIdx.x;
    int col = threadIdx.x;
    float v = (row < NN && col < FF) ? x[(size_t)row * FF + col] : 0.f;
    xpad[(size_t)row * 320 + col] = f2bf(v);
}

__global__ void wprep_feat(const float* __restrict__ W, unsigned short* __restrict__ Bt) {
    int n = blockIdx.x;
    int k = threadIdx.x;
    float v = (k < FF) ? W[(size_t)k * HH + n] : 0.f;
    Bt[(size_t)n * 320 + k] = f2bf(v);
}

__global__ void wprep_layer(const float* __restrict__ skipW, const float* __restrict__ gcnW,
                            unsigned short* __restrict__ Bt) {
    int idx = blockIdx.x * blockDim.x + threadIdx.x;
    int n = idx >> 10, k = idx & 1023;
    int seg = k >> 8, k2 = k & 255;
    float v = (seg == 0) ? skipW[(size_t)k2 * HH + n]
                         : gcnW[(size_t)(seg - 1) * HH * HH + (size_t)k2 * HH + n] * (1.0f / 3.0f);
    Bt[(size_t)n * 1024 + k] = f2bf(v);
}

__global__ void bias_layer(const float* __restrict__ skip_b, const float* __restrict__ gcn_b,
                           float* __restrict__ bias) {
    int t = threadIdx.x;
    bias[t] = skip_b[t] + (gcn_b[t] + gcn_b[HH + t] + gcn_b[2 * HH + t]) * (1.0f / 3.0f);
}

__global__ void wprep_c1(const float* __restrict__ W, unsigned short* __restrict__ Bt) {
    int idx = blockIdx.x * blockDim.x + threadIdx.x;
    int n = idx >> 8, k = idx & 255;
    Bt[(size_t)n * HH + k] = f2bf(W[(size_t)k * HH + n]);
}

__global__ void wprep_c2(const float* __restrict__ W, unsigned short* __restrict__ Bt) {
    int n = blockIdx.x;
    int k = threadIdx.x;
    float v = (n < CC) ? W[(size_t)k * CC + n] : 0.f;
    Bt[(size_t)n * HH + k] = f2bf(v);
}

// ---------------------------------------------------------------------------
// Aggregation (bf16): grid (NN/4, RR). One wave per dst node.
// Scalar-pipe edge stream; gather address = SGPR base + lane offset.
// ---------------------------------------------------------------------------
__global__ __launch_bounds__(256) void agg_bf16(unsigned short* __restrict__ hcat,
                                                const int* __restrict__ offs_all,
                                                const int2* __restrict__ srcw_all,
                                                const float* __restrict__ rs_in_all) {
    int r = blockIdx.y;
    const int* offs = offs_all + (size_t)r * (NN + 1);
    const int2* srcw = srcw_all + (size_t)r * EE;
    const float* rs_i = rs_in_all + (size_t)r * NN;
    int wave = threadIdx.x >> 6;
    int lane = threadIdx.x & 63;
    int node = blockIdx.x * 4 + wave;
    if (node >= NN) return;
    int s0 = __builtin_amdgcn_readfirstlane(offs[node]);
    int s1 = __builtin_amdgcn_readfirstlane(offs[node + 1]);
    int cnt = s1 - s0;
    const int2* ew = srcw + s0;
    const unsigned short* hb = hcat + lane * 4;
    float a0 = 0.f, a1 = 0.f, a2 = 0.f, a3 = 0.f;
    int k = 0;
    for (; k + 8 <= cnt; k += 8) {
        int2 e[8];
#pragma unroll
        for (int q = 0; q < 8; q++) e[q] = ew[k + q];
        ushort4 hv[8];
#pragma unroll
        for (int q = 0; q < 8; q++) hv[q] = *(const ushort4*)(hb + (size_t)e[q].x * 1024);
#pragma unroll
        for (int q = 0; q < 8; q++) {
            float u = __int_as_float(e[q].y);
            a0 += u * bf2f(hv[q].x); a1 += u * bf2f(hv[q].y);
            a2 += u * bf2f(hv[q].z); a3 += u * bf2f(hv[q].w);
        }
    }
    if (k + 4 <= cnt) {
        int2 e[4];
#pragma unroll
        for (int q = 0; q < 4; q++) e[q] = ew[k + q];
        ushort4 hv[4];
#pragma unroll
        for (int q = 0; q < 4; q++) hv[q] = *(const ushort4*)(hb + (size_t)e[q].x * 1024);
#pragma unroll
        for (int q = 0; q < 4; q++) {
            float u = __int_as_float(e[q].y);
            a0 += u * bf2f(hv[q].x); a1 += u * bf2f(hv[q].y);
            a2 += u * bf2f(hv[q].z); a3 += u * bf2f(hv[q].w);
        }
        k += 4;
    }
    int rem = cnt - k;  // 0..3
    if (rem > 0) {
        int2 e[3];
#pragma unroll
        for (int q = 0; q < 3; q++) {
            int kk = k + q; if (kk > cnt - 1) kk = cnt - 1;
            e[q] = ew[kk];
        }
        ushort4 hv[3];
#pragma unroll
        for (int q = 0; q < 3; q++) hv[q] = *(const ushort4*)(hb + (size_t)e[q].x * 1024);
        float u0 = __int_as_float(e[0].y);
        float u1 = rem > 1 ? __int_as_float(e[1].y) : 0.f;
        float u2 = rem > 2 ? __int_as_float(e[2].y) : 0.f;
        a0 += u0 * bf2f(hv[0].x) + u1 * bf2f(hv[1].x) + u2 * bf2f(hv[2].x);
        a1 += u0 * bf2f(hv[0].y) + u1 * bf2f(hv[1].y) + u2 * bf2f(hv[2].y);
        a2 += u0 * bf2f(hv[0].z) + u1 * bf2f(hv[1].z) + u2 * bf2f(hv[2].z);
        a3 += u0 * bf2f(hv[0].w) + u1 * bf2f(hv[1].w) + u2 * bf2f(hv[2].w);
    }
    float wi = rs_i[node];
    ushort4 o;
    o.x = f2bf(a0 * wi); o.y = f2bf(a1 * wi);
    o.z = f2bf(a2 * wi); o.w = f2bf(a3 * wi);
    *(ushort4*)(hcat + (size_t)node * 1024 + 256 * (r + 1) + lane * 4) = o;
}

// ---------------------------------------------------------------------------
// Barrier-free bf16 MFMA GEMM: no LDS. 128x128 block, 4 waves, each wave
// owns an exclusive 32-row strip x 128 cols (acc 2x8 tiles). A and B frags
// are loaded DIRECTLY from global (16B/lane, full 64B lines); register
// double-buffer gives 1-stage prefetch with fine-grained vmcnt scheduling.
// K must be a multiple of 64. B re-read per wave hits L2 (panel = 512 KB).
// ---------------------------------------------------------------------------
__global__ __launch_bounds__(256) void mfma_gemm(const unsigned short* __restrict__ A, int ldA,
                                                 const unsigned short* __restrict__ Bt,
                                                 const float* __restrict__ bias,
                                                 void* __restrict__ Cv, int ldC,
                                                 int Nstore, int K, int c_bf16,
                                                 float* __restrict__ stats) {
    int tid = threadIdx.x;
    int w = tid >> 6, lane = tid & 63;
    int quad = lane >> 4, lr = lane & 15;
    int bm = blockIdx.y * 128 + w * 32;   // wave-exclusive 32-row strip
    int bn = blockIdx.x * 128;

    const unsigned short* A0p = A + (size_t)(bm + lr) * ldA + quad * 8;
    const unsigned short* A1p = A0p + (size_t)16 * ldA;
    const unsigned short* Bp  = Bt + (size_t)(bn + lr) * K + quad * 8;
    const size_t jstr = (size_t)16 * K;

    f32x4 acc[2][8];
#pragma unroll
    for (int i = 0; i < 2; i++)
#pragma unroll
        for (int j = 0; j < 8; j++) acc[i][j] = (f32x4){0.f, 0.f, 0.f, 0.f};

    bf16x8 a0[2], b0[8], a1[2], b1[8];

#define LOADS(ab, bb, kk) do {                                            \
    ab[0] = *(const bf16x8*)(A0p + (kk));                                 \
    ab[1] = *(const bf16x8*)(A1p + (kk));                                 \
    _Pragma("unroll")                                                     \
    for (int j_ = 0; j_ < 8; j_++)                                        \
        bb[j_] = *(const bf16x8*)(Bp + jstr * j_ + (kk));                 \
} while (0)

#define COMP(ab, bb) do {                                                 \
    _Pragma("unroll")                                                     \
    for (int i_ = 0; i_ < 2; i_++)                                        \
    _Pragma("unroll")                                                     \
    for (int j_ = 0; j_ < 8; j_++)                                        \
        acc[i_][j_] = __builtin_amdgcn_mfma_f32_16x16x32_bf16(            \
            ab[i_], bb[j_], acc[i_][j_], 0, 0, 0);                        \
} while (0)

    LOADS(a0, b0, 0);
    int k0 = 0;
    for (; k0 + 64 < K; k0 += 64) {
        LOADS(a1, b1, k0 + 32);
        COMP(a0, b0);
        LOADS(a0, b0, k0 + 64);
        COMP(a1, b1);
    }
    LOADS(a1, b1, k0 + 32);
    COMP(a0, b0);
    COMP(a1, b1);
#undef LOADS
#undef COMP

    float* Cf = (float*)Cv;
    unsigned short* Cb = (unsigned short*)Cv;
#pragma unroll
    for (int j = 0; j < 8; j++) {
        int col = bn + j * 16 + lr;
        if (col >= Nstore) continue;
        float bv = bias ? bias[col] : 0.f;
        float ssum = 0.f, ssq = 0.f;
#pragma unroll
        for (int i = 0; i < 2; i++) {
#pragma unroll
            for (int v = 0; v < 4; v++) {
                int row = bm + i * 16 + quad * 4 + v;
                if (row < NN) {
                    float val = acc[i][j][v] + bv;
                    if (c_bf16) Cb[(size_t)row * ldC + col] = f2bf(val);
                    else        Cf[(size_t)row * ldC + col] = val;
                    ssum += val; ssq += val * val;
                }
            }
        }
        if (stats) {
            ssum += __shfl_xor(ssum, 16); ssum += __shfl_xor(ssum, 32);
            ssq  += __shfl_xor(ssq, 16);  ssq  += __shfl_xor(ssq, 32);
            if (quad == 0) {
                atomicAdd(&stats[col], ssum);
                atomicAdd(&stats[HH + col], ssq);
            }
        }
    }
}

// ---------------------------------------------------------------------------
// BN: coef precompute + vectorized apply (bf16 in, bf16 out at ld=1024)
// ---------------------------------------------------------------------------
__global__ void bn_coef(const float* __restrict__ stats, const float* __restrict__ g,
                        const float* __restrict__ b, float* __restrict__ coef, float invM) {
    int c = threadIdx.x;
    float mean = stats[c] * invM;
    float var = stats[HH + c] * invM - mean * mean;
    float inv = rsqrtf(var + 1e-5f);
    float sc = g[c] * inv;
    coef[c] = sc;
    coef[HH + c] = b[c] - mean * sc;
}

// act: 1 = relu, 2 = leaky relu (0.01)
__global__ __launch_bounds__(256) void bn_apply_v(const unsigned short* __restrict__ Z,
                                                  const float* __restrict__ coef,
                                                  unsigned short* __restrict__ out, int act) {
    int idx = blockIdx.x * blockDim.x + threadIdx.x;
    if (idx >= NN * 32) return;
    int row = idx >> 5, cg = (idx & 31) * 8;
    union { uint4 u; unsigned short s[8]; } zin, zo;
    zin.u = *(const uint4*)(Z + (size_t)row * HH + cg);
    f32x4 sc0 = *(const f32x4*)(coef + cg);
    f32x4 sc1 = *(const f32x4*)(coef + cg + 4);
    f32x4 sh0 = *(const f32x4*)(coef + HH + cg);
    f32x4 sh1 = *(const f32x4*)(coef + HH + cg + 4);
#pragma unroll
    for (int j = 0; j < 8; j++) {
        float sc = (j < 4) ? sc0[j] : sc1[j - 4];
        float sh = (j < 4) ? sh0[j] : sh1[j - 4];
        float v = bf2f(zin.s[j]) * sc + sh;
        if (act == 1) v = fmaxf(v, 0.f);
        else v = (v < 0.f) ? 0.01f * v : v;
        zo.s[j] = f2bf(v);
    }
    *(uint4*)(out + (size_t)row * 1024 + cg) = zo.u;
}

// ---------------------------------------------------------------------------
extern "C" void kernel_launch(void* const* d_in, const int* in_sizes, int n_in,
                              void* d_out, int out_size, void* d_ws, size_t ws_size,
                              hipStream_t stream) {
    const float* x        = (const float*)d_in[0];
    const int*   esrc     = (const int*)d_in[1];
    const int*   edst     = (const int*)d_in[2];
    const float* W_feat   = (const float*)d_in[3];
    const float* b_feat   = (const float*)d_in[4];
    const float* g_feat   = (const float*)d_in[5];
    const float* beta_feat= (const float*)d_in[6];
    const float* gcn_W    = (const float*)d_in[7];
    const float* gcn_b    = (const float*)d_in[8];
    const float* skip_W   = (const float*)d_in[9];
    const float* skip_b   = (const float*)d_in[10];
    const float* bn_g     = (const float*)d_in[11];
    const float* bn_b     = (const float*)d_in[12];
    const float* W_c1     = (const float*)d_in[13];
    const float* b_c1     = (const float*)d_in[14];
    const float* g_c      = (const float*)d_in[15];
    const float* beta_c   = (const float*)d_in[16];
    const float* W_c2     = (const float*)d_in[17];
    const float* b_c2     = (const float*)d_in[18];
    float* out = (float*)d_out;
    (void)in_sizes; (void)n_in; (void)out_size; (void)ws_size;

    char* w = (char*)d_ws;
    size_t off = 0;
    auto alloc = [&](size_t bytes) { void* p = w + off; off += (bytes + 255) & ~(size_t)255; return p; };
    unsigned short* hcat = (unsigned short*)alloc((size_t)MPAD * 1024 * 2);
    unsigned short* xpad = hcat;  // [MPAD][320] bf16, dead after feat GEMM
    unsigned short* c_acc = (unsigned short*)alloc((size_t)NN * HH * 2);  // bf16 pre-BN C
    float* f_stats = (float*)alloc(4 * 2 * HH * 4);   // 4 slices of [2][HH]
    float* f_coef  = (float*)alloc(2 * HH * 4);
    float* f_rs_out = (float*)alloc((size_t)RR * NN * 4);
    float* f_rs_in  = (float*)alloc((size_t)RR * NN * 4);
    int* i_cnt_out = (int*)alloc((size_t)RR * NN * 4);
    int* i_cnt_in  = (int*)alloc((size_t)RR * NN * 4);
    int* i_off     = (int*)alloc((size_t)RR * (NN + 1) * 4);
    int* i_cur     = (int*)alloc((size_t)RR * NN * 4);
    int2* i_srcw   = (int2*)alloc((size_t)RR * EE * 8);
    int* i_bsum    = (int*)alloc((size_t)RR * SNB * 4);
    unsigned short* Bt_feat = (unsigned short*)alloc(256 * 320 * 2);
    unsigned short* Bt_l0   = (unsigned short*)alloc(256 * 1024 * 2);
    unsigned short* Bt_l1   = (unsigned short*)alloc(256 * 1024 * 2);
    unsigned short* Bt_c1   = (unsigned short*)alloc(256 * 256 * 2);
    unsigned short* Bt_c2   = (unsigned short*)alloc(128 * 256 * 2);
    float* bias_l0 = (float*)alloc(HH * 4);
    float* bias_l1 = (float*)alloc(HH * 4);

    const float invM = 1.0f / (float)NN;
    const int RE = RR * EE;

    // --- CSR + degrees ---
    (void)hipMemsetAsync(i_cnt_out, 0, (size_t)RR * NN * 4, stream);
    (void)hipMemsetAsync(i_cnt_in, 0, (size_t)RR * NN * 4, stream);
    (void)hipMemsetAsync(f_stats, 0, 4 * 2 * HH * 4, stream);
    hist_kernel<<<cdiv_h(RE, 256), 256, 0, stream>>>(esrc, edst, i_cnt_out, i_cnt_in, RE, EE);
    rs_kernel<<<cdiv_h(RR * NN, 256), 256, 0, stream>>>(i_cnt_out, i_cnt_in, f_rs_out, f_rs_in, RR * NN);
    scan_a<<<dim3(SNB, RR), 256, 0, stream>>>(i_cnt_in, i_bsum);
    scan_b<<<1, 64, 0, stream>>>(i_bsum, i_off);
    scan_c<<<dim3(SNB, RR), 256, 0, stream>>>(i_cnt_in, i_bsum, i_off, i_cur);
    fill_kernel<<<cdiv_h(RE, 256), 256, 0, stream>>>(esrc, edst, f_rs_out, i_cur, i_srcw, RE, EE);

    // --- weight prep (bf16, transposed) ---
    convert_x<<<MPAD, 320, 0, stream>>>(x, xpad);
    wprep_feat<<<256, 320, 0, stream>>>(W_feat, Bt_feat);
    wprep_layer<<<1024, 256, 0, stream>>>(skip_W, gcn_W, Bt_l0);
    wprep_layer<<<1024, 256, 0, stream>>>(skip_W + (size_t)HH * HH, gcn_W + (size_t)RR * HH * HH, Bt_l1);
    bias_layer<<<1, 256, 0, stream>>>(skip_b, gcn_b, bias_l0);
    bias_layer<<<1, 256, 0, stream>>>(skip_b + HH, gcn_b + (size_t)RR * HH, bias_l1);
    wprep_c1<<<256, 256, 0, stream>>>(W_c1, Bt_c1);
    wprep_c2<<<128, 256, 0, stream>>>(W_c2, Bt_c2);

    dim3 grid_H(2, MPAD / 128);
    dim3 grid_C(1, MPAD / 128);
    const int nblk_a = cdiv_h(NN * 32, 256);
    float* st0 = f_stats;
    float* st1 = f_stats + 2 * HH;
    float* st2 = f_stats + 4 * HH;
    float* st3 = f_stats + 6 * HH;

    // --- feat_reduce: h = relu(BN(x @ W_feat + b_feat)) -> hcat[:,0:256] bf16 ---
    mfma_gemm<<<grid_H, 256, 0, stream>>>(xpad, 320, Bt_feat, b_feat, c_acc, HH, HH, 320, 1, st0);
    bn_coef<<<1, 256, 0, stream>>>(st0, g_feat, beta_feat, f_coef, invM);
    bn_apply_v<<<nblk_a, 256, 0, stream>>>(c_acc, f_coef, hcat, 1);

    // --- GCN layers: one K=1024 GEMM per layer ---
    for (int l = 0; l < LL; l++) {
        agg_bf16<<<dim3(cdiv_h(NN, 4), RR), 256, 0, stream>>>(hcat, i_off, i_srcw, f_rs_in);
        float* st = l ? st2 : st1;
        mfma_gemm<<<grid_H, 256, 0, stream>>>(hcat, 1024, l ? Bt_l1 : Bt_l0,
                                              l ? bias_l1 : bias_l0, c_acc, HH, HH, 1024, 1, st);
        bn_coef<<<1, 256, 0, stream>>>(st, bn_g + (size_t)l * HH, bn_b + (size_t)l * HH, f_coef, invM);
        bn_apply_v<<<nblk_a, 256, 0, stream>>>(c_acc, f_coef, hcat, 2);
    }

    // --- head ---
    mfma_gemm<<<grid_H, 256, 0, stream>>>(hcat, 1024, Bt_c1, b_c1, c_acc, HH, HH, 256, 1, st3);
    bn_coef<<<1, 256, 0, stream>>>(st3, g_c, beta_c, f_coef, invM);
    bn_apply_v<<<nblk_a, 256, 0, stream>>>(c_acc, f_coef, hcat + 256, 1);
    mfma_gemm<<<grid_C, 256, 0, stream>>>(hcat + 256, 1024, Bt_c2, b_c2, out, CC, CC, 256, 0, nullptr);
}

// Round 8
// 1262.601 us; speedup vs baseline: 1.4425x; 1.4425x over previous
//
#include <hip/hip_runtime.h>

#define NN 100000   // nodes
#define EE 500000   // edges per relation
#define RR 3        // relations
#define LL 2        // layers
#define FF 300      // input features
#define HH 256      // hidden
#define CC 23       // classes
#define MPAD 100096 // 782 * 128
#define SCHUNK 2048
#define SNB ((NN + SCHUNK - 1) / SCHUNK)   // 49

static inline int cdiv_h(int a, int b) { return (a + b - 1) / b; }

typedef __attribute__((ext_vector_type(8))) short bf16x8;
typedef __attribute__((ext_vector_type(4))) float f32x4;

__device__ inline unsigned short f2bf(float f) {
    union { float f; unsigned int u; } v; v.f = f;
    unsigned int r = v.u + 0x7fff + ((v.u >> 16) & 1);
    return (unsigned short)(r >> 16);
}
__device__ inline float bf2f(unsigned short u) {
    union { unsigned int u; float f; } v; v.u = ((unsigned int)u) << 16;
    return v.f;
}
__device__ inline void gl_lds16(const void* g, void* l) {
    __builtin_amdgcn_global_load_lds((const __attribute__((address_space(1))) unsigned int*)g,
                                     (__attribute__((address_space(3))) unsigned int*)l,
                                     16, 0, 0);
}

// ---------------------------------------------------------------------------
// CSR build
// ---------------------------------------------------------------------------
__global__ void hist_kernel(const int* __restrict__ src, const int* __restrict__ dst,
                            int* __restrict__ cnt_out, int* __restrict__ cnt_in,
                            int RE, int Eper) {
    int i = blockIdx.x * blockDim.x + threadIdx.x;
    if (i >= RE) return;
    int r = i / Eper;
    atomicAdd(&cnt_out[r * NN + src[i]], 1);
    atomicAdd(&cnt_in[r * NN + dst[i]], 1);
}

__global__ void rs_kernel(const int* __restrict__ cnt_out, const int* __restrict__ cnt_in,
                          float* __restrict__ rs_out, float* __restrict__ rs_in, int total) {
    int i = blockIdx.x * blockDim.x + threadIdx.x;
    if (i >= total) return;
    rs_out[i] = rsqrtf(fmaxf((float)cnt_out[i], 1.0f));
    rs_in[i]  = rsqrtf(fmaxf((float)cnt_in[i], 1.0f));
}

// --- 3-phase exclusive scan of in-degree counts -> CSR offsets + cursors ---
__global__ __launch_bounds__(256) void scan_a(const int* __restrict__ cnt, int* __restrict__ bsum) {
    int r = blockIdx.y, b = blockIdx.x, t = threadIdx.x;
    const int* c = cnt + (size_t)r * NN;
    int base = b * SCHUNK;
    int s = 0;
    for (int i = t; i < SCHUNK; i += 256) {
        int idx = base + i;
        if (idx < NN) s += c[idx];
    }
#pragma unroll
    for (int o = 1; o < 64; o <<= 1) s += __shfl_xor(s, o);
    __shared__ int sh[4];
    if ((t & 63) == 0) sh[t >> 6] = s;
    __syncthreads();
    if (t == 0) bsum[r * SNB + b] = sh[0] + sh[1] + sh[2] + sh[3];
}

__global__ void scan_b(int* __restrict__ bsum, int* __restrict__ offs) {
    int r = threadIdx.x;
    if (r >= RR) return;
    int* bs = bsum + r * SNB;
    int run = 0;
    for (int i = 0; i < SNB; i++) { int v = bs[i]; bs[i] = run; run += v; }
    offs[(size_t)r * (NN + 1) + NN] = run;
}

__global__ __launch_bounds__(256) void scan_c(const int* __restrict__ cnt, const int* __restrict__ bsum,
                                              int* __restrict__ offs, int* __restrict__ cur) {
    int r = blockIdx.y, b = blockIdx.x, t = threadIdx.x;
    const int* c = cnt + (size_t)r * NN;
    int base = b * SCHUNK + t * 8;
    int v[8]; int s = 0;
#pragma unroll
    for (int j = 0; j < 8; j++) {
        int idx = base + j;
        v[j] = (idx < NN) ? c[idx] : 0;
        s += v[j];
    }
    __shared__ int sh[256];
    sh[t] = s;
    __syncthreads();
    for (int d = 1; d < 256; d <<= 1) {
        int x = (t >= d) ? sh[t - d] : 0;
        __syncthreads();
        sh[t] += x;
        __syncthreads();
    }
    int run = sh[t] - s + bsum[r * SNB + b];
    int* orow = offs + (size_t)r * (NN + 1);
    int* crow = cur + (size_t)r * NN;
#pragma unroll
    for (int j = 0; j < 8; j++) {
        int idx = base + j;
        if (idx < NN) { orow[idx] = run; crow[idx] = run; }
        run += v[j];
    }
}

// Fill packed edge stream: (src, rs_out[src]) per edge, bucketed by dst.
__global__ void fill_kernel(const int* __restrict__ src, const int* __restrict__ dst,
                            const float* __restrict__ rs_out,
                            int* __restrict__ cur, int2* __restrict__ srcw,
                            int RE, int Eper) {
    int i = blockIdx.x * blockDim.x + threadIdx.x;
    if (i >= RE) return;
    int r = i / Eper;
    int d = dst[i];
    int s = src[i];
    float w = rs_out[r * NN + s];
    int pos = atomicAdd(&cur[r * NN + d], 1);
    srcw[(size_t)r * Eper + pos] = make_int2(s, __float_as_int(w));
}

// ---------------------------------------------------------------------------
// Input convert + fused weight prep (single dispatch).
// Segments by blockIdx.x:
//  [0,256)      Bt_feat  [256][320]
//  [256,1280)   Bt_l0    [256][1024]
//  [1280,2304)  Bt_l1    [256][1024]
//  [2304,2560)  Bt_c1    [256][256]
//  [2560,2816)  Bt_c2    [256][256] (rows >= CC zero)
//  2816         bias_l0/l1
// ---------------------------------------------------------------------------
__global__ void convert_x(const float* __restrict__ x, unsigned short* __restrict__ xpad) {
    int row = blockIdx.x;
    int col = threadIdx.x;
    float v = (row < NN && col < FF) ? x[(size_t)row * FF + col] : 0.f;
    xpad[(size_t)row * 320 + col] = f2bf(v);
}

__global__ void prep_weights(const float* __restrict__ W_feat,
                             const float* __restrict__ skip_W, const float* __restrict__ gcn_W,
                             const float* __restrict__ skip_b, const float* __restrict__ gcn_b,
                             const float* __restrict__ W_c1, const float* __restrict__ W_c2,
                             unsigned short* __restrict__ Bt_feat,
                             unsigned short* __restrict__ Bt_l0, unsigned short* __restrict__ Bt_l1,
                             unsigned short* __restrict__ Bt_c1, unsigned short* __restrict__ Bt_c2,
                             float* __restrict__ bias_l0, float* __restrict__ bias_l1) {
    int b = blockIdx.x, t = threadIdx.x;
    if (b < 256) {                       // Bt_feat, n = b
        for (int k = t; k < 320; k += 256) {
            float v = (k < FF) ? W_feat[(size_t)k * HH + b] : 0.f;
            Bt_feat[(size_t)b * 320 + k] = f2bf(v);
        }
    } else if (b < 2304) {               // layer weights
        int l = (b < 1280) ? 0 : 1;
        unsigned short* Bt = l ? Bt_l1 : Bt_l0;
        const float* sW = skip_W + (size_t)l * HH * HH;
        const float* gW = gcn_W + (size_t)l * RR * HH * HH;
        int idx = (b - (l ? 1280 : 256)) * 256 + t;   // 0 .. 256*1024
        int n = idx >> 10, k = idx & 1023;
        int seg = k >> 8, k2 = k & 255;
        float v = (seg == 0) ? sW[(size_t)k2 * HH + n]
                             : gW[(size_t)(seg - 1) * HH * HH + (size_t)k2 * HH + n] * (1.0f / 3.0f);
        Bt[(size_t)n * 1024 + k] = f2bf(v);
    } else if (b < 2560) {               // Bt_c1
        int idx = (b - 2304) * 256 + t;
        int n = idx >> 8, k = idx & 255;
        Bt_c1[(size_t)n * HH + k] = f2bf(W_c1[(size_t)k * HH + n]);
    } else if (b < 2816) {               // Bt_c2 (padded to 256 rows)
        int n = b - 2560, k = t;
        float v = (n < CC) ? W_c2[(size_t)k * CC + n] : 0.f;
        Bt_c2[(size_t)n * HH + k] = f2bf(v);
    } else {                             // biases
        bias_l0[t] = skip_b[t] + (gcn_b[t] + gcn_b[HH + t] + gcn_b[2 * HH + t]) * (1.0f / 3.0f);
        bias_l1[t] = skip_b[HH + t] +
                     (gcn_b[RR * HH + t] + gcn_b[(RR + 1) * HH + t] + gcn_b[(RR + 2) * HH + t]) * (1.0f / 3.0f);
    }
}

// ---------------------------------------------------------------------------
// Aggregation (bf16): grid (NN/4, RR). One wave per dst node.
// Scalar-pipe edge stream; gather address = SGPR base + lane offset.
// ---------------------------------------------------------------------------
__global__ __launch_bounds__(256) void agg_bf16(unsigned short* __restrict__ hcat,
                                                const int* __restrict__ offs_all,
                                                const int2* __restrict__ srcw_all,
                                                const float* __restrict__ rs_in_all) {
    int r = blockIdx.y;
    const int* offs = offs_all + (size_t)r * (NN + 1);
    const int2* srcw = srcw_all + (size_t)r * EE;
    const float* rs_i = rs_in_all + (size_t)r * NN;
    int wave = threadIdx.x >> 6;
    int lane = threadIdx.x & 63;
    int node = blockIdx.x * 4 + wave;
    if (node >= NN) return;
    int s0 = __builtin_amdgcn_readfirstlane(offs[node]);
    int s1 = __builtin_amdgcn_readfirstlane(offs[node + 1]);
    int cnt = s1 - s0;
    const int2* ew = srcw + s0;
    const unsigned short* hb = hcat + lane * 4;
    float a0 = 0.f, a1 = 0.f, a2 = 0.f, a3 = 0.f;
    int k = 0;
    for (; k + 8 <= cnt; k += 8) {
        int2 e[8];
#pragma unroll
        for (int q = 0; q < 8; q++) e[q] = ew[k + q];
        ushort4 hv[8];
#pragma unroll
        for (int q = 0; q < 8; q++) hv[q] = *(const ushort4*)(hb + (size_t)e[q].x * 1024);
#pragma unroll
        for (int q = 0; q < 8; q++) {
            float u = __int_as_float(e[q].y);
            a0 += u * bf2f(hv[q].x); a1 += u * bf2f(hv[q].y);
            a2 += u * bf2f(hv[q].z); a3 += u * bf2f(hv[q].w);
        }
    }
    if (k + 4 <= cnt) {
        int2 e[4];
#pragma unroll
        for (int q = 0; q < 4; q++) e[q] = ew[k + q];
        ushort4 hv[4];
#pragma unroll
        for (int q = 0; q < 4; q++) hv[q] = *(const ushort4*)(hb + (size_t)e[q].x * 1024);
#pragma unroll
        for (int q = 0; q < 4; q++) {
            float u = __int_as_float(e[q].y);
            a0 += u * bf2f(hv[q].x); a1 += u * bf2f(hv[q].y);
            a2 += u * bf2f(hv[q].z); a3 += u * bf2f(hv[q].w);
        }
        k += 4;
    }
    int rem = cnt - k;  // 0..3
    if (rem > 0) {
        int2 e[3];
#pragma unroll
        for (int q = 0; q < 3; q++) {
            int kk = k + q; if (kk > cnt - 1) kk = cnt - 1;
            e[q] = ew[kk];
        }
        ushort4 hv[3];
#pragma unroll
        for (int q = 0; q < 3; q++) hv[q] = *(const ushort4*)(hb + (size_t)e[q].x * 1024);
        float u0 = __int_as_float(e[0].y);
        float u1 = rem > 1 ? __int_as_float(e[1].y) : 0.f;
        float u2 = rem > 2 ? __int_as_float(e[2].y) : 0.f;
        a0 += u0 * bf2f(hv[0].x) + u1 * bf2f(hv[1].x) + u2 * bf2f(hv[2].x);
        a1 += u0 * bf2f(hv[0].y) + u1 * bf2f(hv[1].y) + u2 * bf2f(hv[2].y);
        a2 += u0 * bf2f(hv[0].z) + u1 * bf2f(hv[1].z) + u2 * bf2f(hv[2].z);
        a3 += u0 * bf2f(hv[0].w) + u1 * bf2f(hv[1].w) + u2 * bf2f(hv[2].w);
    }
    float wi = rs_i[node];
    ushort4 o;
    o.x = f2bf(a0 * wi); o.y = f2bf(a1 * wi);
    o.z = f2bf(a2 * wi); o.w = f2bf(a3 * wi);
    *(ushort4*)(hcat + (size_t)node * 1024 + 256 * (r + 1) + lane * 4) = o;
}

// ---------------------------------------------------------------------------
// bf16 MFMA GEMM, 128x256 block (full N per block -> 2x MFMA per staged
// A-byte vs 128x128). BK=64 as two 32-k half-stages (R6 swizzle/staging via
// global_load_lds). 4 waves; wave w owns all 8 m-tiles x 4 n-tiles
// (cols w*64..w*64+63). acc = 128 VGPR. 1-D grid over M (782 blocks).
// K % 64 == 0. Optional fused BN stats; c_bf16 selects C dtype.
// ---------------------------------------------------------------------------
__global__ __launch_bounds__(256, 2) void mfma_gemm(const unsigned short* __restrict__ A, int ldA,
                                                    const unsigned short* __restrict__ Bt,
                                                    const float* __restrict__ bias,
                                                    void* __restrict__ Cv, int ldC,
                                                    int Nstore, int K, int c_bf16,
                                                    float* __restrict__ stats) {
    __shared__ unsigned short ldsA[2][128 * 32];
    __shared__ unsigned short ldsB[2][256 * 32];
    int tid = threadIdx.x;
    int w = tid >> 6, lane = tid & 63;
    int quad = lane >> 4, lr = lane & 15;
    int bm = blockIdx.x * 128;
    int lrow = lane >> 2;
    int lslot = lane & 3;

    f32x4 acc[8][4];
#pragma unroll
    for (int i = 0; i < 8; i++)
#pragma unroll
        for (int j = 0; j < 4; j++) acc[i][j] = (f32x4){0.f, 0.f, 0.f, 0.f};

    for (int k0 = 0; k0 < K; k0 += 64) {
#pragma unroll
        for (int h = 0; h < 2; h++) {
            int kk0 = k0 + h * 32;
#pragma unroll
            for (int c = 0; c < 2; c++) {          // A: 8 chunks of 16 rows
                int cc = w * 2 + c;
                int rA = cc * 16 + lrow;
                int cg = lslot ^ ((rA >> 1) & 3);
                gl_lds16(A + (size_t)(bm + rA) * ldA + kk0 + cg * 8, &ldsA[h][cc * 512]);
            }
#pragma unroll
            for (int c = 0; c < 4; c++) {          // B: 16 chunks of 16 n-rows
                int cc = w * 4 + c;
                int rB = cc * 16 + lrow;
                int cg = lslot ^ ((rB >> 1) & 3);
                gl_lds16(Bt + (size_t)rB * K + kk0 + cg * 8, &ldsB[h][cc * 512]);
            }
        }
        __syncthreads();
#pragma unroll
        for (int h = 0; h < 2; h++) {
            bf16x8 af[8], bfr[4];
#pragma unroll
            for (int i = 0; i < 8; i++) {
                int r = i * 16 + lr;
                int s = quad ^ ((r >> 1) & 3);
                af[i] = *(const bf16x8*)&ldsA[h][r * 32 + s * 8];
            }
#pragma unroll
            for (int j = 0; j < 4; j++) {
                int n = w * 64 + j * 16 + lr;
                int s = quad ^ ((n >> 1) & 3);
                bfr[j] = *(const bf16x8*)&ldsB[h][n * 32 + s * 8];
            }
#pragma unroll
            for (int i = 0; i < 8; i++)
#pragma unroll
                for (int j = 0; j < 4; j++)
                    acc[i][j] = __builtin_amdgcn_mfma_f32_16x16x32_bf16(af[i], bfr[j], acc[i][j], 0, 0, 0);
        }
        __syncthreads();
    }

    float* Cf = (float*)Cv;
    unsigned short* Cb = (unsigned short*)Cv;
#pragma unroll
    for (int j = 0; j < 4; j++) {
        int col = w * 64 + j * 16 + lr;
        if (col >= Nstore) continue;
        float bv = bias ? bias[col] : 0.f;
        float ssum = 0.f, ssq = 0.f;
#pragma unroll
        for (int i = 0; i < 8; i++) {
#pragma unroll
            for (int v = 0; v < 4; v++) {
                int row = bm + i * 16 + quad * 4 + v;
                if (row < NN) {
                    float val = acc[i][j][v] + bv;
                    if (c_bf16) Cb[(size_t)row * ldC + col] = f2bf(val);
                    else        Cf[(size_t)row * ldC + col] = val;
                    ssum += val; ssq += val * val;
                }
            }
        }
        if (stats) {
            ssum += __shfl_xor(ssum, 16); ssum += __shfl_xor(ssum, 32);
            ssq  += __shfl_xor(ssq, 16);  ssq  += __shfl_xor(ssq, 32);
            if (quad == 0) {
                atomicAdd(&stats[col], ssum);
                atomicAdd(&stats[HH + col], ssq);
            }
        }
    }
}

// ---------------------------------------------------------------------------
// BN apply with in-block coef computation (stats -> scale/shift in LDS).
// act: 1 = relu, 2 = leaky relu (0.01). bf16 in [NN][256] -> bf16 out ld=1024.
// ---------------------------------------------------------------------------
__global__ __launch_bounds__(256) void bn_apply_v(const unsigned short* __restrict__ Z,
                                                  const float* __restrict__ stats,
                                                  const float* __restrict__ g,
                                                  const float* __restrict__ b,
                                                  unsigned short* __restrict__ out, int act) {
    __shared__ float sc_s[HH], sh_s[HH];
    int t = threadIdx.x;
    {
        float mean = stats[t] * (1.0f / NN);
        float var = stats[HH + t] * (1.0f / NN) - mean * mean;
        float inv = rsqrtf(var + 1e-5f);
        float sc = g[t] * inv;
        sc_s[t] = sc;
        sh_s[t] = b[t] - mean * sc;
    }
    __syncthreads();
    int idx = blockIdx.x * 256 + t;
    if (idx >= NN * 32) return;
    int row = idx >> 5, cg = (idx & 31) * 8;
    union { uint4 u; unsigned short s[8]; } zin, zo;
    zin.u = *(const uint4*)(Z + (size_t)row * HH + cg);
#pragma unroll
    for (int j = 0; j < 8; j++) {
        float v = bf2f(zin.s[j]) * sc_s[cg + j] + sh_s[cg + j];
        if (act == 1) v = fmaxf(v, 0.f);
        else v = (v < 0.f) ? 0.01f * v : v;
        zo.s[j] = f2bf(v);
    }
    *(uint4*)(out + (size_t)row * 1024 + cg) = zo.u;
}

// ---------------------------------------------------------------------------
extern "C" void kernel_launch(void* const* d_in, const int* in_sizes, int n_in,
                              void* d_out, int out_size, void* d_ws, size_t ws_size,
                              hipStream_t stream) {
    const float* x        = (const float*)d_in[0];
    const int*   esrc     = (const int*)d_in[1];
    const int*   edst     = (const int*)d_in[2];
    const float* W_feat   = (const float*)d_in[3];
    const float* b_feat   = (const float*)d_in[4];
    const float* g_feat   = (const float*)d_in[5];
    const float* beta_feat= (const float*)d_in[6];
    const float* gcn_W    = (const float*)d_in[7];
    const float* gcn_b    = (const float*)d_in[8];
    const float* skip_W   = (const float*)d_in[9];
    const float* skip_b   = (const float*)d_in[10];
    const float* bn_g     = (const float*)d_in[11];
    const float* bn_b     = (const float*)d_in[12];
    const float* W_c1     = (const float*)d_in[13];
    const float* b_c1     = (const float*)d_in[14];
    const float* g_c      = (const float*)d_in[15];
    const float* beta_c   = (const float*)d_in[16];
    const float* W_c2     = (const float*)d_in[17];
    const float* b_c2     = (const float*)d_in[18];
    float* out = (float*)d_out;
    (void)in_sizes; (void)n_in; (void)out_size; (void)ws_size;

    char* w = (char*)d_ws;
    size_t off = 0;
    auto alloc = [&](size_t bytes) { void* p = w + off; off += (bytes + 255) & ~(size_t)255; return p; };
    unsigned short* hcat = (unsigned short*)alloc((size_t)MPAD * 1024 * 2);
    unsigned short* xpad = hcat;  // [MPAD][320] bf16, dead after feat GEMM
    unsigned short* c_acc = (unsigned short*)alloc((size_t)NN * HH * 2);  // bf16 pre-BN C
    float* f_stats = (float*)alloc(4 * 2 * HH * 4);   // 4 slices of [2][HH]
    float* f_rs_out = (float*)alloc((size_t)RR * NN * 4);
    float* f_rs_in  = (float*)alloc((size_t)RR * NN * 4);
    int* i_cnt_out = (int*)alloc((size_t)RR * NN * 4);
    int* i_cnt_in  = (int*)alloc((size_t)RR * NN * 4);
    int* i_off     = (int*)alloc((size_t)RR * (NN + 1) * 4);
    int* i_cur     = (int*)alloc((size_t)RR * NN * 4);
    int2* i_srcw   = (int2*)alloc((size_t)RR * EE * 8);
    int* i_bsum    = (int*)alloc((size_t)RR * SNB * 4);
    unsigned short* Bt_feat = (unsigned short*)alloc(256 * 320 * 2);
    unsigned short* Bt_l0   = (unsigned short*)alloc(256 * 1024 * 2);
    unsigned short* Bt_l1   = (unsigned short*)alloc(256 * 1024 * 2);
    unsigned short* Bt_c1   = (unsigned short*)alloc(256 * 256 * 2);
    unsigned short* Bt_c2   = (unsigned short*)alloc(256 * 256 * 2);  // padded rows >= CC
    float* bias_l0 = (float*)alloc(HH * 4);
    float* bias_l1 = (float*)alloc(HH * 4);

    const int RE = RR * EE;

    // --- CSR + degrees ---
    (void)hipMemsetAsync(i_cnt_out, 0, (size_t)RR * NN * 4, stream);
    (void)hipMemsetAsync(i_cnt_in, 0, (size_t)RR * NN * 4, stream);
    (void)hipMemsetAsync(f_stats, 0, 4 * 2 * HH * 4, stream);
    hist_kernel<<<cdiv_h(RE, 256), 256, 0, stream>>>(esrc, edst, i_cnt_out, i_cnt_in, RE, EE);
    rs_kernel<<<cdiv_h(RR * NN, 256), 256, 0, stream>>>(i_cnt_out, i_cnt_in, f_rs_out, f_rs_in, RR * NN);
    scan_a<<<dim3(SNB, RR), 256, 0, stream>>>(i_cnt_in, i_bsum);
    scan_b<<<1, 64, 0, stream>>>(i_bsum, i_off);
    scan_c<<<dim3(SNB, RR), 256, 0, stream>>>(i_cnt_in, i_bsum, i_off, i_cur);
    fill_kernel<<<cdiv_h(RE, 256), 256, 0, stream>>>(esrc, edst, f_rs_out, i_cur, i_srcw, RE, EE);

    // --- input convert + weight prep ---
    convert_x<<<MPAD, 320, 0, stream>>>(x, xpad);
    prep_weights<<<2817, 256, 0, stream>>>(W_feat, skip_W, gcn_W, skip_b, gcn_b, W_c1, W_c2,
                                           Bt_feat, Bt_l0, Bt_l1, Bt_c1, Bt_c2, bias_l0, bias_l1);

    const int grid_M = MPAD / 128;   // 782
    const int nblk_a = NN * 32 / 256;
    float* st0 = f_stats;
    float* st1 = f_stats + 2 * HH;
    float* st2 = f_stats + 4 * HH;
    float* st3 = f_stats + 6 * HH;

    // --- feat_reduce: h = relu(BN(x @ W_feat + b_feat)) -> hcat[:,0:256] bf16 ---
    mfma_gemm<<<grid_M, 256, 0, stream>>>(xpad, 320, Bt_feat, b_feat, c_acc, HH, HH, 320, 1, st0);
    bn_apply_v<<<nblk_a, 256, 0, stream>>>(c_acc, st0, g_feat, beta_feat, hcat, 1);

    // --- GCN layers: one K=1024 GEMM per layer ---
    for (int l = 0; l < LL; l++) {
        agg_bf16<<<dim3(cdiv_h(NN, 4), RR), 256, 0, stream>>>(hcat, i_off, i_srcw, f_rs_in);
        float* st = l ? st2 : st1;
        mfma_gemm<<<grid_M, 256, 0, stream>>>(hcat, 1024, l ? Bt_l1 : Bt_l0,
                                              l ? bias_l1 : bias_l0, c_acc, HH, HH, 1024, 1, st);
        bn_apply_v<<<nblk_a, 256, 0, stream>>>(c_acc, st, bn_g + (size_t)l * HH,
                                               bn_b + (size_t)l * HH, hcat, 2);
    }

    // --- head ---
    mfma_gemm<<<grid_M, 256, 0, stream>>>(hcat, 1024, Bt_c1, b_c1, c_acc, HH, HH, 256, 1, st3);
    bn_apply_v<<<nblk_a, 256, 0, stream>>>(c_acc, st3, g_c, beta_c, hcat + 256, 1);
    mfma_gemm<<<grid_M, 256, 0, stream>>>(hcat + 256, 1024, Bt_c2, b_c2, out, CC, CC, 256, 0, nullptr);
}